// Round 1
// baseline (275.460 us; speedup 1.0000x reference)
//
#include <hip/hip_runtime.h>

// ExponentialUnitNorm: out = x / sqrt(scan(s_t = 0.01*|x_t| + 0.99*s_{t-1}))
// Shapes fixed by the reference: x [16,1,2000,481,2] fp32, init_state [481] fp32.
//
// Strategy: chunk T into C=8 chunks of 250; each chunk warms up over the
// preceding 500 timesteps (exact for chunks 0-2; truncation err 0.99^500
// ~ 6.6e-3 relative in s -> ~3e-3 relative in out, far under threshold).
// Lanes map to consecutive f -> fully coalesced float2 accesses.

#define ALPHA_F 0.99f
#define OMA_F   0.01f

constexpr int Bn = 16;
constexpr int Tn = 2000;
constexpr int Fn = 481;
constexpr int CHUNKS = 8;
constexpr int LCHUNK = Tn / CHUNKS;  // 250
constexpr int WARM = 500;            // multiple of UNROLL
constexpr int UNROLL = 10;           // 250 % 10 == 0, 500 % 10 == 0

__global__ __launch_bounds__(256) void eun_kernel(
    const float* __restrict__ x,
    const float* __restrict__ init_state,
    float* __restrict__ out) {
  const int f = blockIdx.x * blockDim.x + threadIdx.x;
  if (f >= Fn) return;
  const int b = blockIdx.y;
  const int c = blockIdx.z;

  const int start = c * LCHUNK;
  const int end   = start + LCHUNK;
  const int w     = (start - WARM > 0) ? (start - WARM) : 0;

  // Exact init-state contribution at warm-up start: s_{w-1} includes a^w * s0.
  float s = init_state[f];
  if (w > 0) s *= __powf(ALPHA_F, (float)w);

  const size_t stride = (size_t)Fn * 2;  // floats per timestep
  const float* xp = x   + ((size_t)b * Tn + w)     * stride + (size_t)f * 2;
  float*       op = out + ((size_t)b * Tn + start) * stride + (size_t)f * 2;

  // Warm-up: advance the EMA without storing. Trip count (start-w) is a
  // multiple of UNROLL by construction.
  for (int t0 = w; t0 < start; t0 += UNROLL) {
    float2 v[UNROLL];
#pragma unroll
    for (int j = 0; j < UNROLL; ++j)
      v[j] = *(const float2*)(xp + (size_t)j * stride);
#pragma unroll
    for (int j = 0; j < UNROLL; ++j) {
      float m = sqrtf(fmaxf(v[j].x * v[j].x + v[j].y * v[j].y, 1e-14f));
      s = fmaf(ALPHA_F, s, OMA_F * m);
    }
    xp += (size_t)UNROLL * stride;
  }

  // Main: EMA + normalize + store.
  for (int t0 = start; t0 < end; t0 += UNROLL) {
    float2 v[UNROLL];
#pragma unroll
    for (int j = 0; j < UNROLL; ++j)
      v[j] = *(const float2*)(xp + (size_t)j * stride);
    float2 o[UNROLL];
#pragma unroll
    for (int j = 0; j < UNROLL; ++j) {
      float m = sqrtf(fmaxf(v[j].x * v[j].x + v[j].y * v[j].y, 1e-14f));
      s = fmaf(ALPHA_F, s, OMA_F * m);
      float inv = rsqrtf(s);
      o[j] = make_float2(v[j].x * inv, v[j].y * inv);
    }
#pragma unroll
    for (int j = 0; j < UNROLL; ++j)
      *(float2*)(op + (size_t)j * stride) = o[j];
    xp += (size_t)UNROLL * stride;
    op += (size_t)UNROLL * stride;
  }
}

extern "C" void kernel_launch(void* const* d_in, const int* in_sizes, int n_in,
                              void* d_out, int out_size, void* d_ws, size_t ws_size,
                              hipStream_t stream) {
  const float* x    = (const float*)d_in[0];
  const float* init = (const float*)d_in[1];
  float* out        = (float*)d_out;

  dim3 grid((Fn + 255) / 256, Bn, CHUNKS);  // 2 x 16 x 8 = 256 blocks
  eun_kernel<<<grid, dim3(256), 0, stream>>>(x, init, out);
}

// Round 2
// 252.468 us; speedup vs baseline: 1.0911x; 1.0911x over previous
//
#include <hip/hip_runtime.h>

// ExponentialUnitNorm via exact two-pass parallel scan of the linear EMA
// recurrence s_t = a*s_{t-1} + (1-a)*|x_t|.
//
// Pass 1: 50 chunks of L=40 along T; each (b,c,f) thread computes the chunk's
//         local partial B_c (scan seeded with 0) -> workspace [B,NC,F].
// Pass 2: s_start(c) = s0*aL^c + sum_j B_j*aL^(c-1-j) via Horner over the
//         (L2-resident, 1.5 MB) partials, then rescan chunk + normalize+store.
// Exact up to fp reordering. Parallelism: 1600 blocks/pass (~25 waves/CU).

#define ALPHA_F 0.99f
#define OMA_F   0.01f

constexpr int Bn = 16;
constexpr int Tn = 2000;
constexpr int Fn = 481;
constexpr int NC = 50;          // chunks along T
constexpr int L  = Tn / NC;     // 40
constexpr int UN = 10;          // unroll; L % UN == 0
#define ALPHA_L 0.668971758f    // 0.99^40

__global__ __launch_bounds__(256) void eun_pass1(
    const float* __restrict__ x, float* __restrict__ part) {
  const int f = blockIdx.x * blockDim.x + threadIdx.x;
  if (f >= Fn) return;
  const int b = blockIdx.y;
  const int c = blockIdx.z;

  const size_t stride = (size_t)Fn * 2;
  const float* xp = x + ((size_t)b * Tn + (size_t)c * L) * stride + (size_t)f * 2;

  float s = 0.f;
  for (int t0 = 0; t0 < L; t0 += UN) {
    float2 v[UN];
#pragma unroll
    for (int j = 0; j < UN; ++j)
      v[j] = *(const float2*)(xp + (size_t)j * stride);
#pragma unroll
    for (int j = 0; j < UN; ++j) {
      float m = sqrtf(fmaxf(v[j].x * v[j].x + v[j].y * v[j].y, 1e-14f));
      s = fmaf(ALPHA_F, s, OMA_F * m);
    }
    xp += (size_t)UN * stride;
  }
  part[((size_t)b * NC + c) * Fn + f] = s;
}

__global__ __launch_bounds__(256) void eun_pass2(
    const float* __restrict__ x, const float* __restrict__ init_state,
    const float* __restrict__ part, float* __restrict__ out) {
  const int f = blockIdx.x * blockDim.x + threadIdx.x;
  if (f >= Fn) return;
  const int b = blockIdx.y;
  const int c = blockIdx.z;

  // Horner-combine preceding chunk partials into this chunk's start state.
  // s_start = ((s0*aL + B0)*aL + B1)*aL + ... + B_{c-1}
  float s = init_state[f];
  const float* pp = part + (size_t)b * NC * Fn + f;
  for (int j = 0; j < c; ++j)
    s = fmaf(s, ALPHA_L, pp[(size_t)j * Fn]);

  const size_t stride = (size_t)Fn * 2;
  const float* xp = x   + ((size_t)b * Tn + (size_t)c * L) * stride + (size_t)f * 2;
  float*       op = out + ((size_t)b * Tn + (size_t)c * L) * stride + (size_t)f * 2;

  for (int t0 = 0; t0 < L; t0 += UN) {
    float2 v[UN];
#pragma unroll
    for (int j = 0; j < UN; ++j)
      v[j] = *(const float2*)(xp + (size_t)j * stride);
    float2 o[UN];
#pragma unroll
    for (int j = 0; j < UN; ++j) {
      float m = sqrtf(fmaxf(v[j].x * v[j].x + v[j].y * v[j].y, 1e-14f));
      s = fmaf(ALPHA_F, s, OMA_F * m);
      float inv = rsqrtf(s);
      o[j] = make_float2(v[j].x * inv, v[j].y * inv);
    }
#pragma unroll
    for (int j = 0; j < UN; ++j)
      *(float2*)(op + (size_t)j * stride) = o[j];
    xp += (size_t)UN * stride;
    op += (size_t)UN * stride;
  }
}

extern "C" void kernel_launch(void* const* d_in, const int* in_sizes, int n_in,
                              void* d_out, int out_size, void* d_ws, size_t ws_size,
                              hipStream_t stream) {
  const float* x    = (const float*)d_in[0];
  const float* init = (const float*)d_in[1];
  float* out        = (float*)d_out;
  float* part       = (float*)d_ws;  // needs NC*Bn*Fn*4 = 1.54 MB

  dim3 grid((Fn + 255) / 256, Bn, NC);  // 2 x 16 x 50 = 1600 blocks
  eun_pass1<<<grid, dim3(256), 0, stream>>>(x, part);
  eun_pass2<<<grid, dim3(256), 0, stream>>>(x, init, part, out);
}

// Round 3
// 242.403 us; speedup vs baseline: 1.1364x; 1.0415x over previous
//
#include <hip/hip_runtime.h>

// ExponentialUnitNorm, exact 3-phase parallel scan:
//   pass1: per-chunk local partials B[b,c,f]          (reads x: 123 MB HBM)
//   mid:   chunk-start states start[b,c,f] via serial
//          in-register scan over c (3 MB traffic)
//   pass2: rescan chunk + normalize + NT-store out    (x re-read from L3)
// Comparison is bf16-quantized (harness), so fp reordering is far below
// threshold; measured absmax 0.03125 = 1 bf16 ulp (noise floor).

#define ALPHA_F 0.99f
#define OMA_F   0.01f

constexpr int Bn = 16;
constexpr int Tn = 2000;
constexpr int Fn = 481;
constexpr int NC = 50;          // chunks along T
constexpr int L  = Tn / NC;     // 40
constexpr int UN = 10;          // unroll; L % UN == 0
#define ALPHA_L 0.668971758f    // 0.99^40

__global__ __launch_bounds__(256) void eun_pass1(
    const float* __restrict__ x, float* __restrict__ part) {
  const int f = blockIdx.x * blockDim.x + threadIdx.x;
  if (f >= Fn) return;
  const int b = blockIdx.y;
  const int c = blockIdx.z;

  const size_t stride = (size_t)Fn * 2;
  const float* xp = x + ((size_t)b * Tn + (size_t)c * L) * stride + (size_t)f * 2;

  float s = 0.f;
  for (int t0 = 0; t0 < L; t0 += UN) {
    float2 v[UN];
#pragma unroll
    for (int j = 0; j < UN; ++j)
      v[j] = *(const float2*)(xp + (size_t)j * stride);
#pragma unroll
    for (int j = 0; j < UN; ++j) {
      float m = sqrtf(fmaxf(v[j].x * v[j].x + v[j].y * v[j].y, 1e-14f));
      s = fmaf(ALPHA_F, s, OMA_F * m);
    }
    xp += (size_t)UN * stride;
  }
  part[((size_t)b * NC + c) * Fn + f] = s;
}

// start[b,c,f] = state entering chunk c. 50 independent (unrolled) loads per
// thread -> all in flight; serial combine is 50 register FMAs.
__global__ __launch_bounds__(256) void eun_mid(
    const float* __restrict__ part, const float* __restrict__ init_state,
    float* __restrict__ start) {
  const int f = blockIdx.x * blockDim.x + threadIdx.x;
  if (f >= Fn) return;
  const int b = blockIdx.y;

  const float* pp = part + (size_t)b * NC * Fn + f;
  float p[NC];
#pragma unroll
  for (int c = 0; c < NC; ++c) p[c] = pp[(size_t)c * Fn];

  float s = init_state[f];
  float* sp = start + (size_t)b * NC * Fn + f;
#pragma unroll
  for (int c = 0; c < NC; ++c) {
    sp[(size_t)c * Fn] = s;
    s = fmaf(s, ALPHA_L, p[c]);  // s_begin(c+1) = aL*s_begin(c) + B_c
  }
}

__global__ __launch_bounds__(256) void eun_pass2(
    const float* __restrict__ x, const float* __restrict__ start,
    float* __restrict__ out) {
  const int f = blockIdx.x * blockDim.x + threadIdx.x;
  if (f >= Fn) return;
  const int b = blockIdx.y;
  const int c = blockIdx.z;

  float s = start[((size_t)b * NC + c) * Fn + f];

  const size_t stride = (size_t)Fn * 2;
  const size_t off = ((size_t)b * Tn + (size_t)c * L) * stride + (size_t)f * 2;
  const float* xp = x + off;
  float*       op = out + off;

  for (int t0 = 0; t0 < L; t0 += UN) {
    float2 v[UN];
#pragma unroll
    for (int j = 0; j < UN; ++j)
      v[j] = *(const float2*)(xp + (size_t)j * stride);
#pragma unroll
    for (int j = 0; j < UN; ++j) {
      float m = sqrtf(fmaxf(v[j].x * v[j].x + v[j].y * v[j].y, 1e-14f));
      s = fmaf(ALPHA_F, s, OMA_F * m);
      float inv = rsqrtf(s);
      union { float2 f2; unsigned long long u; } cvt;
      cvt.f2 = make_float2(v[j].x * inv, v[j].y * inv);
      // out is never re-read: bypass L2/L3 so x stays resident for reuse.
      __builtin_nontemporal_store(cvt.u,
          (unsigned long long*)(op + (size_t)j * stride));
    }
    xp += (size_t)UN * stride;
    op += (size_t)UN * stride;
  }
}

extern "C" void kernel_launch(void* const* d_in, const int* in_sizes, int n_in,
                              void* d_out, int out_size, void* d_ws, size_t ws_size,
                              hipStream_t stream) {
  const float* x    = (const float*)d_in[0];
  const float* init = (const float*)d_in[1];
  float* out        = (float*)d_out;
  float* part       = (float*)d_ws;                          // 1.54 MB
  float* start      = (float*)d_ws + (size_t)Bn * NC * Fn;   // 1.54 MB

  dim3 grid3((Fn + 255) / 256, Bn, NC);  // 2 x 16 x 50 = 1600 blocks
  eun_pass1<<<grid3, dim3(256), 0, stream>>>(x, part);
  eun_mid<<<dim3((Fn + 255) / 256, Bn), dim3(256), 0, stream>>>(part, init, start);
  eun_pass2<<<grid3, dim3(256), 0, stream>>>(x, start, out);
}